// Round 1
// baseline (590.134 us; speedup 1.0000x reference)
//
#include <hip/hip_runtime.h>
#include <hip/hip_bf16.h>
#include <stdint.h>
#include <stddef.h>

#define DIMV 2048
#define CTXV 512
#define BV   8192
#define NPV  512
#define NSV  256

typedef __attribute__((ext_vector_type(8))) __bf16 bf16x8;
typedef __attribute__((ext_vector_type(4))) float f32x4;

enum { EPI_BIAS = 0, EPI_RELU = 1, EPI_SUBR = 2, EPI_FILT = 3 };

// C[m][n] = sum_k A[m][k] * W[n][k]  (A: M x K row-major, W: N x K row-major)
// Tile: 128x128, TK=32. 256 threads = 4 waves in 2x2, each wave 64x64 (4x4 MFMA frags).
// LDS layout: 16B chunks, chunk index c = kslot*132 + row (132 pad -> 2-way max bank alias).
// Dual-source A/W: element k < ks comes from (A,ldA), else from (A2,ldA2) at k-ks.
template <int EPI>
__global__ __launch_bounds__(256)
void pe_gemm(const float* __restrict__ A, int ldA,
             const float* __restrict__ A2, int ldA2, int ksA,
             const float* __restrict__ W, int ldW,
             const float* __restrict__ W2, int ldW2, int ksW,
             int N, int K,
             const float* __restrict__ p0, const float* __restrict__ p1,
             const float* __restrict__ p2, float* __restrict__ out)
{
    __shared__ __bf16 ldsA[528 * 8];   // 4 kslots * 132 * 8 bf16
    __shared__ __bf16 ldsB[528 * 8];

    const int tid  = threadIdx.x;
    const int wave = tid >> 6;
    const int lane = tid & 63;
    const int lhi  = lane >> 4;     // kslot for frag reads
    const int llo  = lane & 15;
    const int wr   = wave >> 1;     // wave row 0..1
    const int wc   = wave & 1;      // wave col 0..1
    const int m0   = blockIdx.x * 128;
    const int n0   = blockIdx.y * 128;

    const f32x4 fzero = {0.f, 0.f, 0.f, 0.f};
    f32x4 acc[4][4];
#pragma unroll
    for (int i = 0; i < 4; ++i)
#pragma unroll
        for (int j = 0; j < 4; ++j)
            acc[i][j] = fzero;

    const int row_w = tid >> 2;   // 0..63
    const int ks_w  = tid & 3;    // kslot this thread stages

    for (int k0 = 0; k0 < K; k0 += 32) {
        __syncthreads();
        const int kg = k0 + ks_w * 8;
#pragma unroll
        for (int h = 0; h < 2; ++h) {
            const int row = row_w + h * 64;
            // ---- stage A tile ----
            {
                const float* src;
                if (kg < ksA) src = A  + (size_t)(m0 + row) * ldA  + kg;
                else          src = A2 + (size_t)(m0 + row) * ldA2 + (kg - ksA);
                f32x4 v0 = *(const f32x4*)src;
                f32x4 v1 = *(const f32x4*)(src + 4);
                bf16x8 cv;
#pragma unroll
                for (int e = 0; e < 4; ++e) { cv[e] = (__bf16)v0[e]; cv[e + 4] = (__bf16)v1[e]; }
                *(bf16x8*)(&ldsA[(ks_w * 132 + row) * 8]) = cv;
            }
            // ---- stage W tile ----
            {
                const float* src;
                if (kg < ksW) src = W  + (size_t)(n0 + row) * ldW  + kg;
                else          src = W2 + (size_t)(n0 + row) * ldW2 + (kg - ksW);
                f32x4 v0 = *(const f32x4*)src;
                f32x4 v1 = *(const f32x4*)(src + 4);
                bf16x8 cv;
#pragma unroll
                for (int e = 0; e < 4; ++e) { cv[e] = (__bf16)v0[e]; cv[e + 4] = (__bf16)v1[e]; }
                *(bf16x8*)(&ldsB[(ks_w * 132 + row) * 8]) = cv;
            }
        }
        __syncthreads();

        bf16x8 af[4], bfr[4];
#pragma unroll
        for (int i = 0; i < 4; ++i)
            af[i]  = *(const bf16x8*)(&ldsA[(lhi * 132 + wr * 64 + i * 16 + llo) * 8]);
#pragma unroll
        for (int j = 0; j < 4; ++j)
            bfr[j] = *(const bf16x8*)(&ldsB[(lhi * 132 + wc * 64 + j * 16 + llo) * 8]);
#pragma unroll
        for (int i = 0; i < 4; ++i)
#pragma unroll
            for (int j = 0; j < 4; ++j)
                acc[i][j] = __builtin_amdgcn_mfma_f32_16x16x32_bf16(af[i], bfr[j], acc[i][j], 0, 0, 0);
    }

    // epilogue: C/D layout col = lane&15, row = (lane>>4)*4 + reg  [m89-verified]
#pragma unroll
    for (int i = 0; i < 4; ++i) {
#pragma unroll
        for (int j = 0; j < 4; ++j) {
            const int colg = n0 + wc * 64 + j * 16 + llo;
#pragma unroll
            for (int r = 0; r < 4; ++r) {
                const int rowg = m0 + wr * 64 + i * 16 + lhi * 4 + r;
                const size_t idx = (size_t)rowg * N + colg;
                float v = acc[i][j][r];
                if constexpr (EPI == EPI_BIAS)      v = v + p0[colg];
                else if constexpr (EPI == EPI_RELU) v = fmaxf(v, 0.f);
                else if constexpr (EPI == EPI_SUBR) v = fmaxf(p0[idx] - v, 0.f);
                else /* EPI_FILT */                 v = 0.9f * p2[idx] + 0.1f * fmaxf(p0[idx] - p1[idx] - v, 0.f);
                out[idx] = v;
            }
        }
    }
}

extern "C" void kernel_launch(void* const* d_in, const int* in_sizes, int n_in,
                              void* d_out, int out_size, void* d_ws, size_t ws_size,
                              hipStream_t stream) {
    (void)in_sizes; (void)n_in; (void)out_size; (void)ws_size;

    const float* x       = (const float*)d_in[0];
    const float* ctx     = (const float*)d_in[1];
    const float* r_pos   = (const float*)d_in[2];
    const float* r_neg   = (const float*)d_in[3];
    const float* Wpred   = (const float*)d_in[4];
    const float* bpred   = (const float*)d_in[5];
    const float* Wpv1    = (const float*)d_in[6];
    const float* Wpv2    = (const float*)d_in[7];
    const float* Wvip    = (const float*)d_in[8];
    const float* Wsomin  = (const float*)d_in[9];
    const float* Wvipsom = (const float*)d_in[10];
    const float* Wpepos  = (const float*)d_in[11];
    const float* Wpeneg  = (const float*)d_in[12];
    const float* Wsomd   = (const float*)d_in[13];

    float* pred = (float*)d_ws;                      // B x 2048
    float* rpv1 = pred + (size_t)BV * DIMV;          // B x 512
    float* rpv2 = rpv1 + (size_t)BV * NPV;           // B x 512
    float* rvip = rpv2 + (size_t)BV * NPV;           // B x 256
    float* ssom = rvip + (size_t)BV * NSV;           // B x 256
    float* rsom = ssom + (size_t)BV * NSV;           // B x 256

    float* out_pos = (float*)d_out;
    float* out_neg = out_pos + (size_t)BV * DIMV;

    dim3 blk(256);

    // 1. predicted = ctx @ Wpred^T + b_pred        (M=8192,N=2048,K=512)
    pe_gemm<EPI_BIAS><<<dim3(64, 16), blk, 0, stream>>>(
        ctx, CTXV, nullptr, 0, CTXV,
        Wpred, CTXV, nullptr, 0, CTXV,
        DIMV, CTXV, bpred, nullptr, nullptr, pred);

    // 2. r_pv1 = relu(x @ Wpv1^T)                  (N=512,K=2048)
    pe_gemm<EPI_RELU><<<dim3(64, 4), blk, 0, stream>>>(
        x, DIMV, nullptr, 0, DIMV,
        Wpv1, DIMV, nullptr, 0, DIMV,
        NPV, DIMV, nullptr, nullptr, nullptr, rpv1);

    // 3. s_som = relu(x @ Wsomin^T)                (N=256,K=2048)
    pe_gemm<EPI_RELU><<<dim3(64, 2), blk, 0, stream>>>(
        x, DIMV, nullptr, 0, DIMV,
        Wsomin, DIMV, nullptr, 0, DIMV,
        NSV, DIMV, nullptr, nullptr, nullptr, ssom);

    // 4. r_pv2 = relu(pred @ Wpv2^T)               (N=512,K=2048)
    pe_gemm<EPI_RELU><<<dim3(64, 4), blk, 0, stream>>>(
        pred, DIMV, nullptr, 0, DIMV,
        Wpv2, DIMV, nullptr, 0, DIMV,
        NPV, DIMV, nullptr, nullptr, nullptr, rpv2);

    // 5. r_vip = relu(pred @ Wvip^T)               (N=256,K=2048)
    pe_gemm<EPI_RELU><<<dim3(64, 2), blk, 0, stream>>>(
        pred, DIMV, nullptr, 0, DIMV,
        Wvip, DIMV, nullptr, 0, DIMV,
        NSV, DIMV, nullptr, nullptr, nullptr, rvip);

    // 6. r_som = relu(ssom - rvip @ Wvipsom^T)     (N=256,K=256)
    pe_gemm<EPI_SUBR><<<dim3(64, 2), blk, 0, stream>>>(
        rvip, NSV, nullptr, 0, NSV,
        Wvipsom, NSV, nullptr, 0, NSV,
        NSV, NSV, ssom, nullptr, nullptr, rsom);

    // 7. new_r_pos = 0.9*r_pos + 0.1*relu(x - pred - rpv2 @ Wpepos^T)   (N=2048,K=512)
    pe_gemm<EPI_FILT><<<dim3(64, 16), blk, 0, stream>>>(
        rpv2, NPV, nullptr, 0, NPV,
        Wpepos, NPV, nullptr, 0, NPV,
        DIMV, NPV, x, pred, r_pos, out_pos);

    // 8. new_r_neg = 0.9*r_neg + 0.1*relu(pred - x - [rpv1|rsom] @ [Wpeneg|Wsomd]^T)
    //    concat-K GEMM: K=768, split at 512
    pe_gemm<EPI_FILT><<<dim3(64, 16), blk, 0, stream>>>(
        rpv1, NPV, rsom, NSV, NPV,
        Wpeneg, NPV, Wsomd, NSV, NPV,
        DIMV, NPV + NSV, pred, x, r_neg, out_neg);
}

// Round 2
// 353.865 us; speedup vs baseline: 1.6677x; 1.6677x over previous
//
#include <hip/hip_runtime.h>
#include <hip/hip_bf16.h>
#include <stdint.h>
#include <stddef.h>

#define DIMV 2048
#define CTXV 512
#define BV   8192
#define NPV  512
#define NSV  256

typedef __attribute__((ext_vector_type(8))) __bf16 bf16x8;
typedef __attribute__((ext_vector_type(4))) float f32x4;

enum { EPI_BIAS = 0, EPI_RELU = 1, EPI_SUBR = 2, EPI_FILT = 3 };

__device__ __forceinline__ void gload_lds16(const void* g, void* l) {
    __builtin_amdgcn_global_load_lds(
        (const __attribute__((address_space(1))) unsigned int*)g,
        (__attribute__((address_space(3))) unsigned int*)l,
        16, 0, 0);
}

// ---------------------------------------------------------------------------
// Batched fp32 -> bf16 convert for x, ctx, and the 9 weight matrices.
// Segment sizes are compile-time constants (units: chunks of 8 elements).
// ---------------------------------------------------------------------------
struct CvtArgs {
    const float* src[11];
    __bf16*      dst[11];
};

__global__ __launch_bounds__(256) void cvt_all(CvtArgs a) {
    constexpr int NSEG = 11;
    // chunk (8-elem) cumulative offsets:
    // x, ctx, Wpred, Wpv1, Wpv2, Wvip, Wsomin, Wvipsom, Wpepos, Wpeneg, Wsomd
    constexpr unsigned cum[NSEG + 1] = {
        0u, 2097152u, 2621440u, 2752512u, 2883584u, 3014656u,
        3080192u, 3145728u, 3153920u, 3284992u, 3416064u, 3481600u};
    const unsigned total = cum[NSEG];
    for (unsigned c = blockIdx.x * blockDim.x + threadIdx.x; c < total;
         c += gridDim.x * blockDim.x) {
        const float* sp = a.src[0];
        __bf16*      dp = a.dst[0];
        unsigned     base = 0;
#pragma unroll
        for (int t = 1; t < NSEG; ++t) {
            const bool g = (c >= cum[t]);
            sp   = g ? a.src[t] : sp;
            dp   = g ? a.dst[t] : dp;
            base = g ? cum[t] : base;
        }
        const unsigned off = (c - base) * 8u;
        f32x4 v0 = *(const f32x4*)(sp + off);
        f32x4 v1 = *(const f32x4*)(sp + off + 4);
        bf16x8 o;
#pragma unroll
        for (int e = 0; e < 4; ++e) { o[e] = (__bf16)v0[e]; o[e + 4] = (__bf16)v1[e]; }
        *(bf16x8*)(dp + off) = o;
    }
}

// ---------------------------------------------------------------------------
// bf16 MFMA GEMM: C[m][n] = sum_k A[m][k] * W[n][k]
// 128x128 tile, BK=32, 4 waves (2x2), 16x16x32 MFMA, m97 structure:
//   global_load_lds(16B) staging into linear LDS, read-side XOR swizzle
//   (chunk ^= (row>>1)&3) realized by pre-swizzling the GLOBAL source addr.
// Supports K-concat on A and W (split at ksA/ksW) and N-concat on W
// (region boundary NB1 -> W2/out2).
// ---------------------------------------------------------------------------
template <int EPI>
__global__ __launch_bounds__(256)
void pe_gemm(const __bf16* __restrict__ A, int ldA,
             const __bf16* __restrict__ A2, int ldA2, int ksA,
             const __bf16* __restrict__ W1, int ldW1,
             const __bf16* __restrict__ W1k2, int ldW1k2, int ksW,
             const __bf16* __restrict__ W2, int ldW2,
             int NB1, int N1cols, int N2cols, int K, int nbx,
             const float* __restrict__ bias,
             const __bf16* __restrict__ subp,
             const __bf16* __restrict__ predb, const float* __restrict__ xf,
             float sgn, const float* __restrict__ rold,
             void* __restrict__ out1, void* __restrict__ out2)
{
    __shared__ __align__(16) __bf16 ldsA[128 * 32];
    __shared__ __align__(16) __bf16 ldsB[128 * 32];
    char* ldsAb = (char*)ldsA;
    char* ldsBb = (char*)ldsB;

    // XCD-aware bijective swizzle (all grids are multiples of 8)
    const int nwg = gridDim.x;
    const int bid = blockIdx.x;
    const int wg  = (bid & 7) * (nwg >> 3) + (bid >> 3);
    const int bx  = wg % nbx;
    const int by  = wg / nbx;
    const int m0  = bx * 128;
    const int n0  = by * 128;

    // N-region resolve (block-uniform; NB1 is a multiple of 128)
    const bool reg2   = (W2 != nullptr) && (n0 >= NB1);
    const __bf16* Wa  = reg2 ? W2 : W1;
    const __bf16* Wb  = W1k2;
    const int wlda    = reg2 ? ldW2 : ldW1;
    const int wldb    = ldW1k2;
    const int kswcur  = reg2 ? K : ksW;
    const int nrow0   = reg2 ? (n0 - NB1) : n0;

    const int tid  = threadIdx.x;
    const int wave = tid >> 6;
    const int lane = tid & 63;
    const int lhi  = lane >> 4;
    const int llo  = lane & 15;
    const int wr   = wave >> 1;
    const int wc   = wave & 1;

    const f32x4 fzero = {0.f, 0.f, 0.f, 0.f};
    f32x4 acc[4][4];
#pragma unroll
    for (int i = 0; i < 4; ++i)
#pragma unroll
        for (int j = 0; j < 4; ++j) acc[i][j] = fzero;

    const int rins = lane >> 2;   // row within a 16-row staging instruction
    const int ch   = lane & 3;    // physical 16B chunk within the 64B row

    for (int k0 = 0; k0 < K; k0 += 32) {
        __syncthreads();
        // each wave stages 32 rows of A and 32 rows of B (2 insts each)
#pragma unroll
        for (int half = 0; half < 2; ++half) {
            const int rt = wave * 32 + half * 16 + rins;      // tile row 0..127
            const int kc = ch ^ ((rt >> 1) & 3);              // logical k-chunk (swizzle)
            const int kg = k0 + kc * 8;
            {
                const __bf16* src = (kg < ksA)
                    ? A  + (size_t)(m0 + rt) * ldA  + kg
                    : A2 + (size_t)(m0 + rt) * ldA2 + (kg - ksA);
                gload_lds16(src, ldsAb + wave * 2048 + half * 1024);
            }
            {
                const __bf16* src = (kg < kswcur)
                    ? Wa + (size_t)(nrow0 + rt) * wlda + kg
                    : Wb + (size_t)(nrow0 + rt) * wldb + (kg - kswcur);
                gload_lds16(src, ldsBb + wave * 2048 + half * 1024);
            }
        }
        __syncthreads();

        bf16x8 af[4], bfr[4];
#pragma unroll
        for (int i = 0; i < 4; ++i) {
            const int r  = wr * 64 + i * 16 + llo;
            const int pc = lhi ^ ((r >> 1) & 3);
            af[i] = *(const bf16x8*)(ldsAb + r * 64 + pc * 16);
        }
#pragma unroll
        for (int j = 0; j < 4; ++j) {
            const int r  = wc * 64 + j * 16 + llo;
            const int pc = lhi ^ ((r >> 1) & 3);
            bfr[j] = *(const bf16x8*)(ldsBb + r * 64 + pc * 16);
        }
#pragma unroll
        for (int i = 0; i < 4; ++i)
#pragma unroll
            for (int j = 0; j < 4; ++j)
                acc[i][j] = __builtin_amdgcn_mfma_f32_16x16x32_bf16(af[i], bfr[j], acc[i][j], 0, 0, 0);
    }

    // epilogue: C/D layout col = lane&15, row = (lane>>4)*4 + reg
#pragma unroll
    for (int i = 0; i < 4; ++i) {
#pragma unroll
        for (int j = 0; j < 4; ++j) {
            const int colg = n0 + wc * 64 + j * 16 + llo;
#pragma unroll
            for (int r = 0; r < 4; ++r) {
                const int rowg = m0 + wr * 64 + i * 16 + lhi * 4 + r;
                float v = acc[i][j][r];
                if constexpr (EPI == EPI_BIAS) {
                    v += bias[colg];
                    ((__bf16*)out1)[(size_t)rowg * N1cols + colg] = (__bf16)v;
                } else if constexpr (EPI == EPI_RELU) {
                    v = fmaxf(v, 0.f);
                    if (colg < NB1)
                        ((__bf16*)out1)[(size_t)rowg * N1cols + colg] = (__bf16)v;
                    else
                        ((__bf16*)out2)[(size_t)rowg * N2cols + (colg - NB1)] = (__bf16)v;
                } else if constexpr (EPI == EPI_SUBR) {
                    const size_t idx = (size_t)rowg * N1cols + colg;
                    v = fmaxf((float)subp[idx] - v, 0.f);
                    ((__bf16*)out1)[idx] = (__bf16)v;
                } else { // EPI_FILT
                    const size_t idx = (size_t)rowg * 2048 + colg;
                    const float d = sgn * (xf[idx] - (float)predb[idx]) - v;
                    ((float*)out1)[idx] = 0.9f * rold[idx] + 0.1f * fmaxf(d, 0.f);
                }
            }
        }
    }
}

extern "C" void kernel_launch(void* const* d_in, const int* in_sizes, int n_in,
                              void* d_out, int out_size, void* d_ws, size_t ws_size,
                              hipStream_t stream) {
    (void)in_sizes; (void)n_in; (void)out_size; (void)ws_size;

    const float* x       = (const float*)d_in[0];
    const float* ctx     = (const float*)d_in[1];
    const float* r_pos   = (const float*)d_in[2];
    const float* r_neg   = (const float*)d_in[3];
    const float* Wpred   = (const float*)d_in[4];
    const float* bpred   = (const float*)d_in[5];
    const float* Wpv1    = (const float*)d_in[6];
    const float* Wpv2    = (const float*)d_in[7];
    const float* Wvip    = (const float*)d_in[8];
    const float* Wsomin  = (const float*)d_in[9];
    const float* Wvipsom = (const float*)d_in[10];
    const float* Wpepos  = (const float*)d_in[11];
    const float* Wpeneg  = (const float*)d_in[12];
    const float* Wsomd   = (const float*)d_in[13];

    char* ws = (char*)d_ws;
    __bf16* x_bf      = (__bf16*)ws; ws += (size_t)BV * DIMV * 2;
    __bf16* ctx_bf    = (__bf16*)ws; ws += (size_t)BV * CTXV * 2;
    __bf16* pred_bf   = (__bf16*)ws; ws += (size_t)BV * DIMV * 2;
    __bf16* rpv1_bf   = (__bf16*)ws; ws += (size_t)BV * NPV * 2;
    __bf16* rpv2_bf   = (__bf16*)ws; ws += (size_t)BV * NPV * 2;
    __bf16* rvip_bf   = (__bf16*)ws; ws += (size_t)BV * NSV * 2;
    __bf16* ssom_bf   = (__bf16*)ws; ws += (size_t)BV * NSV * 2;
    __bf16* rsom_bf   = (__bf16*)ws; ws += (size_t)BV * NSV * 2;
    __bf16* Wpred_bf  = (__bf16*)ws; ws += (size_t)DIMV * CTXV * 2;
    __bf16* Wpv1_bf   = (__bf16*)ws; ws += (size_t)NPV * DIMV * 2;
    __bf16* Wpv2_bf   = (__bf16*)ws; ws += (size_t)NPV * DIMV * 2;
    __bf16* Wvip_bf   = (__bf16*)ws; ws += (size_t)NSV * DIMV * 2;
    __bf16* Wsomin_bf = (__bf16*)ws; ws += (size_t)NSV * DIMV * 2;
    __bf16* Wvipsom_bf= (__bf16*)ws; ws += (size_t)NSV * NSV * 2;
    __bf16* Wpepos_bf = (__bf16*)ws; ws += (size_t)DIMV * NPV * 2;
    __bf16* Wpeneg_bf = (__bf16*)ws; ws += (size_t)DIMV * NPV * 2;
    __bf16* Wsomd_bf  = (__bf16*)ws; ws += (size_t)DIMV * NSV * 2;

    float* out_pos = (float*)d_out;
    float* out_neg = out_pos + (size_t)BV * DIMV;

    // 0. batched convert
    CvtArgs ca;
    ca.src[0] = x;       ca.dst[0] = x_bf;
    ca.src[1] = ctx;     ca.dst[1] = ctx_bf;
    ca.src[2] = Wpred;   ca.dst[2] = Wpred_bf;
    ca.src[3] = Wpv1;    ca.dst[3] = Wpv1_bf;
    ca.src[4] = Wpv2;    ca.dst[4] = Wpv2_bf;
    ca.src[5] = Wvip;    ca.dst[5] = Wvip_bf;
    ca.src[6] = Wsomin;  ca.dst[6] = Wsomin_bf;
    ca.src[7] = Wvipsom; ca.dst[7] = Wvipsom_bf;
    ca.src[8] = Wpepos;  ca.dst[8] = Wpepos_bf;
    ca.src[9] = Wpeneg;  ca.dst[9] = Wpeneg_bf;
    ca.src[10] = Wsomd;  ca.dst[10] = Wsomd_bf;
    cvt_all<<<dim3(2048), dim3(256), 0, stream>>>(ca);

    dim3 blk(256);

    // 1. pred_bf = bf16(ctx @ Wpred^T + b_pred)           grid 64x16
    pe_gemm<EPI_BIAS><<<dim3(1024), blk, 0, stream>>>(
        ctx_bf, CTXV, nullptr, 0, CTXV,
        Wpred_bf, CTXV, nullptr, 0, CTXV, nullptr, 0,
        DIMV, DIMV, 0, CTXV, 64,
        bpred, nullptr, nullptr, nullptr, 0.f, nullptr, pred_bf, nullptr);

    // 2+3. [rpv1 | ssom] = relu(x @ [Wpv1 | Wsomin]^T)    N-concat 512+256, grid 64x6
    pe_gemm<EPI_RELU><<<dim3(384), blk, 0, stream>>>(
        x_bf, DIMV, nullptr, 0, DIMV,
        Wpv1_bf, DIMV, nullptr, 0, DIMV, Wsomin_bf, DIMV,
        NPV, NPV, NSV, DIMV, 64,
        nullptr, nullptr, nullptr, nullptr, 0.f, nullptr, rpv1_bf, ssom_bf);

    // 4+5. [rpv2 | rvip] = relu(pred @ [Wpv2 | Wvip]^T)   grid 64x6
    pe_gemm<EPI_RELU><<<dim3(384), blk, 0, stream>>>(
        pred_bf, DIMV, nullptr, 0, DIMV,
        Wpv2_bf, DIMV, nullptr, 0, DIMV, Wvip_bf, DIMV,
        NPV, NPV, NSV, DIMV, 64,
        nullptr, nullptr, nullptr, nullptr, 0.f, nullptr, rpv2_bf, rvip_bf);

    // 6. rsom = relu(ssom - rvip @ Wvipsom^T)             grid 64x2
    pe_gemm<EPI_SUBR><<<dim3(128), blk, 0, stream>>>(
        rvip_bf, NSV, nullptr, 0, NSV,
        Wvipsom_bf, NSV, nullptr, 0, NSV, nullptr, 0,
        NSV, NSV, 0, NSV, 64,
        nullptr, ssom_bf, nullptr, nullptr, 0.f, nullptr, rsom_bf, nullptr);

    // 7. out_pos = 0.9*r_pos + 0.1*relu(x - pred - rpv2 @ Wpepos^T)  grid 64x16
    pe_gemm<EPI_FILT><<<dim3(1024), blk, 0, stream>>>(
        rpv2_bf, NPV, nullptr, 0, NPV,
        Wpepos_bf, NPV, nullptr, 0, NPV, nullptr, 0,
        DIMV, DIMV, 0, NPV, 64,
        nullptr, nullptr, pred_bf, x, 1.f, r_pos, out_pos, nullptr);

    // 8. out_neg = 0.9*r_neg + 0.1*relu(pred - x - [rpv1|rsom] @ [Wpeneg|Wsomd]^T)
    //    K-concat 512+256, grid 64x16
    pe_gemm<EPI_FILT><<<dim3(1024), blk, 0, stream>>>(
        rpv1_bf, NPV, rsom_bf, NSV, NPV,
        Wpeneg_bf, NPV, Wsomd_bf, NSV, NPV, nullptr, 0,
        DIMV, DIMV, 0, NPV + NSV, 64,
        nullptr, nullptr, pred_bf, x, -1.f, r_neg, out_neg, nullptr);
}